// Round 20
// baseline (2454.275 us; speedup 1.0000x reference)
//
#include <hip/hip_runtime.h>
#include <stdint.h>

#define TT 8192
#define HD 2048
#define FFN 5632
#define NE 8
#define NPK 11264   // packed [w1|w2] rows per expert (2*FFN)

typedef float f32x4 __attribute__((ext_vector_type(4)));
typedef _Float16 f16x8 __attribute__((ext_vector_type(8)));
typedef unsigned int u32;

// workspace layout (bytes)
#define OFF_WR    0ul
#define OFF_CNT   65536ul
#define OFF_LISTS 66048ul
#define OFF_TOKW  328192ul
#define OFF_ACT   1048576ul                    // 16384*5632*2      = 184549376
#define OFF_XH    (OFF_ACT + 184549376ul)      // 8192*2048*2       = 33554432
#define OFF_WPK   (OFF_XH + 33554432ul)        // 8*11264*2048*2    = 369098752
#define OFF_W3H   OFF_WPK                      // fc2h reuses WPK (stream-ordered)

__device__ __forceinline__ void gl_lds16(const void* g, void* s) {
  __builtin_amdgcn_global_load_lds((const __attribute__((address_space(1))) u32*)g,
                                   (__attribute__((address_space(3))) u32*)s, 16, 0, 0);
}

__device__ __forceinline__ f16x8 cvt8(f32x4 a, f32x4 b) {
  f16x8 r;
  r[0] = (_Float16)a[0]; r[1] = (_Float16)a[1]; r[2] = (_Float16)a[2]; r[3] = (_Float16)a[3];
  r[4] = (_Float16)b[0]; r[5] = (_Float16)b[1]; r[6] = (_Float16)b[2]; r[7] = (_Float16)b[3];
  return r;
}

__global__ __launch_bounds__(256) void k_cvt(const float* __restrict__ in,
                                             _Float16* __restrict__ out, long n8) {
  long i = (long)blockIdx.x * 256 + threadIdx.x;
  const long stride = (long)gridDim.x * 256;
  for (; i < n8; i += stride) {
    f32x4 a = ((const f32x4*)in)[i * 2];
    f32x4 b = ((const f32x4*)in)[i * 2 + 1];
    ((f16x8*)out)[i] = cvt8(a, b);
  }
}

// pack [fc1_1 | fc1_2] -> wpk for 256-col tiles (verified R16/R17)
__global__ __launch_bounds__(256) void k_cvtpack(const float* __restrict__ fc11,
                                                 const float* __restrict__ fc12,
                                                 _Float16* __restrict__ wpk) {
  const long total = (long)NE * NPK * 256;  // 8-elem chunks
  long i8 = (long)blockIdx.x * 256 + threadIdx.x;
  const long stride = (long)gridDim.x * 256;
  for (; i8 < total; i8 += stride) {
    int k8 = (int)(i8 & 255);
    long qe = i8 >> 8;
    int q = (int)(qe % NPK);
    int e = (int)(qe / NPK);
    int c = q & 255;
    int f = (q >> 8) * 128 + ((c >> 6) & 3) * 32 + ((c >> 4) & 1) * 16 + (c & 15);
    const float* src = ((c >> 5) & 1 ? fc12 : fc11) + ((size_t)e * FFN + f) * HD + k8 * 8;
    f32x4 a = *(const f32x4*)src;
    f32x4 b = *(const f32x4*)(src + 4);
    *(f16x8*)(wpk + qe * HD + (size_t)k8 * 8) = cvt8(a, b);
  }
}

__global__ __launch_bounds__(256) void k_prep(const float* __restrict__ wg,
                                              const float* __restrict__ wge,
                                              float* __restrict__ wr) {
  int i = blockIdx.x * 256 + threadIdx.x;
  if (i < HD * NE) wr[i] = 0.5f * (wge[i] + wg[i]);
}

// router + fused x -> fp16 conversion
__global__ __launch_bounds__(256) void k_router(const float* __restrict__ x,
                                                const float* __restrict__ wr,
                                                float* __restrict__ logits,
                                                float* __restrict__ tokw,
                                                int* __restrict__ lists,
                                                int* __restrict__ cnt,
                                                _Float16* __restrict__ xh) {
  const int t = blockIdx.x, tid = threadIdx.x;
  const float* xr = x + (size_t)t * HD;
  _Float16* xo = xh + (size_t)t * HD;
  float acc[NE];
#pragma unroll
  for (int e = 0; e < NE; ++e) acc[e] = 0.f;
  for (int h = tid; h < HD; h += 256) {
    float xv = xr[h];
    xo[h] = (_Float16)xv;
    const float* w = wr + h * NE;
#pragma unroll
    for (int e = 0; e < NE; ++e) acc[e] = fmaf(xv, w[e], acc[e]);
  }
#pragma unroll
  for (int e = 0; e < NE; ++e)
#pragma unroll
    for (int off = 32; off; off >>= 1)
      acc[e] += __shfl_xor(acc[e], off, 64);
  __shared__ float red[4][NE];
  int wv = tid >> 6;
  if ((tid & 63) == 0)
    for (int e = 0; e < NE; ++e) red[wv][e] = acc[e];
  __syncthreads();
  if (tid == 0) {
    float l[NE];
#pragma unroll
    for (int e = 0; e < NE; ++e) l[e] = red[0][e] + red[1][e] + red[2][e] + red[3][e];
#pragma unroll
    for (int e = 0; e < NE; ++e) logits[(size_t)t * NE + e] = l[e];
    int i0 = 0;
    for (int e = 1; e < NE; ++e) if (l[e] > l[i0]) i0 = e;
    int i1 = -1;
    for (int e = 0; e < NE; ++e) if (e != i0 && (i1 < 0 || l[e] > l[i1])) i1 = e;
    float p1 = __expf(l[i1] - l[i0]);
    float s = 1.f + p1;
    tokw[t * 2]     = 1.f / s;
    tokw[t * 2 + 1] = p1 / s;
    int q0 = atomicAdd(&cnt[i0], 1);
    lists[i0 * TT + q0] = t * 2;
    int q1 = atomicAdd(&cnt[i1], 1);
    lists[i1 * TT + q1] = t * 2 + 1;
  }
}

// ====== Stage A (register-direct B): act = silu(h1)*h2, h = xh @ wpk^T ======
// 256x256 tile, BK=32, 512 thr, 8 waves 2Mx4N (wave 128x64), mfma 16x16x32.
// A: 2-buffer LDS via gl_lds (XOR chunk-perm, conflict-free). B: straight
// global->VGPR ping-pong (prefetch 1 step) — removes 1/3 of LDS reads.
// No manual vmcnt: __syncthreads drains A-DMA and B loads (compiler-emitted).
__global__ __launch_bounds__(512, 2) void k_ffn1(const _Float16* __restrict__ xh,
                                                 const _Float16* __restrict__ wpk,
                                                 const int* __restrict__ lists,
                                                 const int* __restrict__ cnt,
                                                 _Float16* __restrict__ act) {
  const int bid = blockIdx.x;
  const int xk = bid & 7;
  const int sq = bid >> 3;                 // 0..1407
  const int slot = sq / 88;                // 0..15
  const int within = sq - slot * 88;
  const int ct = within >> 1;              // 0..43
  const int rt_in = within & 1;
  const int e = slot & 7;
  const int r = ((xk - e) & 7) + ((slot >> 3) << 3);  // 0..15
  const int rt = r * 2 + rt_in;            // 0..31
  const int count = cnt[e];
  if (rt * 256 >= count) return;
  const int tid = threadIdx.x, lane = tid & 63, wv = tid >> 6;

  __shared__ __align__(16) _Float16 As[2][8192];   // 2 x (256 rows x 32 k)
  __shared__ int row_pair[256];

  if (tid < 256) {
    int rg = rt * 256 + tid;
    row_pair[tid] = (rg < count) ? lists[e * TT + rg] : -1;
  }
  __syncthreads();

  // A staging (verified R17): wave wv rows wv*16..+15 and +128, XOR chunk perm
  const int lr = lane >> 2;
  const int r0 = wv * 16 + lr;                          // 0..127
  const int cp = (((lane & 3) ^ ((r0 >> 1) & 3))) * 8;  // +128 rows: same perm
  const int pr0 = row_pair[r0], pr1 = row_pair[r0 + 128];
  const _Float16* gA0 = xh + (size_t)(pr0 >= 0 ? (pr0 >> 1) : 0) * HD + cp;
  const _Float16* gA1 = xh + (size_t)(pr1 >= 0 ? (pr1 >> 1) : 0) * HD + cp;

  auto stgA = [&](int b, int k0) {
    gl_lds16(gA0 + k0, &As[b][wv * 512]);
    gl_lds16(gA1 + k0, &As[b][4096 + wv * 512]);
  };

  const f32x4 z4 = {0.f, 0.f, 0.f, 0.f};
  f32x4 acc[8][4];
#pragma unroll
  for (int m = 0; m < 8; ++m)
#pragma unroll
    for (int n = 0; n < 4; ++n) acc[m][n] = z4;

  const int fr = lane & 15, kq = lane >> 4;
  const int wm = wv >> 2, wn = wv & 3;
  int aoff[8];
#pragma unroll
  for (int m = 0; m < 8; ++m) {
    int R = wm * 128 + m * 16 + fr;
    aoff[m] = R * 32 + (kq ^ ((R >> 1) & 3)) * 8;
  }
  // B direct: fragment (row = ct*256 + wn*64 + n*16 + fr, k = s*32 + kq*8)
  const _Float16* gb[4];
#pragma unroll
  for (int n = 0; n < 4; ++n) {
    int grow = ct * 256 + wn * 64 + n * 16 + fr;
    gb[n] = wpk + ((size_t)e * NPK + grow) * HD + kq * 8;
  }

  f16x8 fb0[4], fb1[4];
#define BLOAD(FB, S)                                                        \
  {                                                                         \
    _Pragma("unroll") for (int n = 0; n < 4; ++n)                           \
        FB[n] = *(const f16x8*)(gb[n] + (S) * 32);                          \
  }

  // prologue: stage K-step 0 (A via DMA, B via regs); barrier drains both
  stgA(0, 0);
  BLOAD(fb0, 0);
  __syncthreads();

  const int NS = HD / 32;  // 64 (even)
#define STEP(S, CUR, NXT)                                                   \
  {                                                                         \
    const int buf = (S) & 1;                                                \
    if ((S) + 1 < NS) { stgA(buf ^ 1, ((S) + 1) * 32); BLOAD(NXT, (S) + 1); } \
    f16x8 fa[8];                                                            \
    _Pragma("unroll") for (int m = 0; m < 8; ++m)                           \
        fa[m] = *(const f16x8*)&As[buf][aoff[m]];                           \
    __builtin_amdgcn_s_setprio(1);                                          \
    _Pragma("unroll") for (int m = 0; m < 8; ++m)                           \
      _Pragma("unroll") for (int n = 0; n < 4; ++n)                         \
          acc[m][n] = __builtin_amdgcn_mfma_f32_16x16x32_f16(               \
              fa[m], CUR[n], acc[m][n], 0, 0, 0);                           \
    __builtin_amdgcn_s_setprio(0);                                          \
    __syncthreads();                                                        \
  }

  for (int s = 0; s < NS; s += 2) {
    STEP(s, fb0, fb1);
    STEP(s + 1, fb1, fb0);
  }
#undef STEP
#undef BLOAD

  // epilogue (verified R16/R17): mat pairing n (h1) <-> n+2 (h2)
  const int rbase = wm * 128 + kq * 4;
#pragma unroll
  for (int m = 0; m < 8; ++m) {
#pragma unroll
    for (int n = 0; n < 2; ++n) {
      const int f = ct * 128 + wn * 32 + n * 16 + fr;
#pragma unroll
      for (int j = 0; j < 4; ++j) {
        int rl = rbase + m * 16 + j;
        int pr = row_pair[rl];
        if (pr >= 0) {
          float h1 = acc[m][n][j], h2 = acc[m][n + 2][j];
          float sv = h1 / (1.f + __expf(-h1));
          act[(size_t)pr * FFN + f] = (_Float16)(sv * h2);
        }
      }
    }
  }
}

// ============ Stage B: out += w * (act @ w3h^T). R12-exact: 192x128, wave 96x64 ============
__global__ __launch_bounds__(256, 3) void k_ffn2(const _Float16* __restrict__ act,
                                                 const _Float16* __restrict__ w3h,
                                                 const int* __restrict__ lists,
                                                 const int* __restrict__ cnt,
                                                 const float* __restrict__ tokw,
                                                 float* __restrict__ out) {
  const int bid = blockIdx.x;
  const int xk = bid & 7;
  const int sq = bid >> 3;                 // 0..703
  const int e = sq / 88;                   // 0..7
  const int within = sq - e * 88;
  const int rt = within >> 1;              // 0..43
  const int ct = (((xk - e) & 7) << 1) + (within & 1);  // 0..15
  const int count = cnt[e];
  if (rt * 192 >= count) return;
  const int tid = threadIdx.x, lane = tid & 63, wv = tid >> 6;

  __shared__ __align__(16) _Float16 As[2][6144];
  __shared__ __align__(16) _Float16 Bs[2][4096];
  __shared__ int row_pair[192];
  __shared__ float row_w[192];

  if (tid < 192) {
    int rg = rt * 192 + tid;
    int pr = (rg < count) ? lists[e * TT + rg] : -1;
    row_pair[tid] = pr;
    row_w[tid] = (pr >= 0) ? tokw[pr] : 0.f;
  }
  __syncthreads();

  const int lr = lane >> 2;
  const int srowA = wv * 48 + lr;
  const int cpA = (lane & 3) ^ ((srowA >> 1) & 3);
  const int pA0 = row_pair[srowA], pA1 = row_pair[srowA + 16], pA2 = row_pair[srowA + 32];
  const _Float16* gA0 = act + (size_t)(pA0 >= 0 ? pA0 : 0) * FFN + cpA * 8;
  const _Float16* gA1 = act + (size_t)(pA1 >= 0 ? pA1 : 0) * FFN + cpA * 8;
  const _Float16* gA2 = act + (size_t)(pA2 >= 0 ? pA2 : 0) * FFN + cpA * 8;
  const int srowB = wv * 32 + lr;
  const int cpB = (lane & 3) ^ ((srowB >> 1) & 3);
  const _Float16* gB0 = w3h + ((size_t)e * HD + (size_t)ct * 128 + srowB) * FFN + cpB * 8;
  const _Float16* gB1 = gB0 + (size_t)16 * FFN;

  auto stage = [&](int sl, int k0) {
    gl_lds16(gA0 + k0, &As[sl][wv * 1536]);
    gl_lds16(gA1 + k0, &As[sl][wv * 1536 + 512]);
    gl_lds16(gA2 + k0, &As[sl][wv * 1536 + 1024]);
    gl_lds16(gB0 + k0, &Bs[sl][wv * 1024]);
    gl_lds16(gB1 + k0, &Bs[sl][wv * 1024 + 512]);
  };

  const f32x4 z4 = {0.f, 0.f, 0.f, 0.f};
  f32x4 acc[6][4];
#pragma unroll
  for (int m = 0; m < 6; ++m)
#pragma unroll
    for (int n = 0; n < 4; ++n) acc[m][n] = z4;

  const int fr = lane & 15, kq = lane >> 4;
  const int wrow = (wv >> 1) * 96, wcol = (wv & 1) * 64;
  int aoff[6], boff[4];
#pragma unroll
  for (int m = 0; m < 6; ++m) {
    int rr = wrow + m * 16 + fr;
    aoff[m] = rr * 32 + (kq ^ ((rr >> 1) & 3)) * 8;
  }
#pragma unroll
  for (int n = 0; n < 4; ++n) {
    int rr = wcol + n * 16 + fr;
    boff[n] = rr * 32 + (kq ^ ((rr >> 1) & 3)) * 8;
  }

  stage(0, 0);
  __syncthreads();

  const int NS = FFN / 32;  // 176
  for (int ks = 0; ks < NS; ++ks) {
    const int buf = ks & 1;
    if (ks + 1 < NS) stage(buf ^ 1, (ks + 1) * 32);
    f16x8 fa[6], fb[4];
#pragma unroll
    for (int m = 0; m < 6; ++m) fa[m] = *(const f16x8*)&As[buf][aoff[m]];
#pragma unroll
    for (int n = 0; n < 4; ++n) fb[n] = *(const f16x8*)&Bs[buf][boff[n]];
    __builtin_amdgcn_s_setprio(1);
#pragma unroll
    for (int m = 0; m < 6; ++m)
#pragma unroll
      for (int n = 0; n < 4; ++n)
        acc[m][n] = __builtin_amdgcn_mfma_f32_16x16x32_f16(fa[m], fb[n], acc[m][n], 0, 0, 0);
    __builtin_amdgcn_s_setprio(0);
    __syncthreads();
  }

  const int rbase = wrow + kq * 4;
#pragma unroll
  for (int m = 0; m < 6; ++m) {
#pragma unroll
    for (int n = 0; n < 4; ++n) {
      const int col = ct * 128 + wcol + n * 16 + fr;
#pragma unroll
      for (int j = 0; j < 4; ++j) {
        int rl = rbase + m * 16 + j;
        int pr = row_pair[rl];
        if (pr >= 0) {
          float v = acc[m][n][j] * row_w[rl];
          unsafeAtomicAdd(out + (size_t)(pr >> 1) * HD + col, v);
        }
      }
    }
  }
}

extern "C" void kernel_launch(void* const* d_in, const int* in_sizes, int n_in,
                              void* d_out, int out_size, void* d_ws, size_t ws_size,
                              hipStream_t stream) {
  (void)in_sizes; (void)n_in; (void)out_size; (void)ws_size;
  const float* x    = (const float*)d_in[0];
  const float* wg   = (const float*)d_in[1];
  const float* wge  = (const float*)d_in[2];
  const float* fc11 = (const float*)d_in[3];
  const float* fc12 = (const float*)d_in[4];
  const float* fc2  = (const float*)d_in[5];
  float* out    = (float*)d_out;
  float* logits = out + (size_t)TT * HD;

  char* ws = (char*)d_ws;
  float* wr      = (float*)(ws + OFF_WR);
  int*   cnt     = (int*)(ws + OFF_CNT);
  int*   lists   = (int*)(ws + OFF_LISTS);
  float* tokw    = (float*)(ws + OFF_TOKW);
  _Float16* act  = (_Float16*)(ws + OFF_ACT);
  _Float16* xh   = (_Float16*)(ws + OFF_XH);
  _Float16* wpk  = (_Float16*)(ws + OFF_WPK);
  _Float16* w3h  = (_Float16*)(ws + OFF_W3H);

  hipMemsetAsync(out, 0, (size_t)TT * HD * sizeof(float), stream);
  hipMemsetAsync(cnt, 0, NE * sizeof(int), stream);

  k_prep<<<dim3((HD * NE + 255) / 256), 256, 0, stream>>>(wg, wge, wr);
  k_router<<<dim3(TT), 256, 0, stream>>>(x, wr, logits, tokw, lists, cnt, xh);

  k_cvtpack<<<dim3(2048), 256, 0, stream>>>(fc11, fc12, wpk);

  // grid = xk(8) x slot(16) x within(88); 512 threads (8 waves)
  k_ffn1<<<dim3(8 * 16 * 88), 512, 0, stream>>>(xh, wpk, lists, cnt, act);

  // w3h reuses the wpk region — stream-ordered after ffn1 finished reading it
  k_cvt<<<dim3(2048), 256, 0, stream>>>(fc2, w3h, (long)NE * HD * FFN / 8);

  k_ffn2<<<dim3(8 * 8 * 88), 256, 0, stream>>>(act, w3h, lists, cnt, tokw, out);
}

// Round 21
// 1909.011 us; speedup vs baseline: 1.2856x; 1.2856x over previous
//
#include <hip/hip_runtime.h>
#include <stdint.h>

#define TT 8192
#define HD 2048
#define FFN 5632
#define NE 8
#define NPK 11264   // packed [w1|w2] rows per expert (2*FFN)

typedef float f32x4 __attribute__((ext_vector_type(4)));
typedef _Float16 f16x8 __attribute__((ext_vector_type(8)));
typedef unsigned int u32;

// workspace layout (bytes)
#define OFF_WR    0ul
#define OFF_CNT   65536ul
#define OFF_LISTS 66048ul
#define OFF_TOKW  328192ul
#define OFF_ACT   1048576ul                    // 16384*5632*2      = 184549376
#define OFF_XH    (OFF_ACT + 184549376ul)      // 8192*2048*2       = 33554432
#define OFF_WPK   (OFF_XH + 33554432ul)        // 8*11264*2048*2    = 369098752
#define OFF_W3H   OFF_WPK                      // fc2h reuses WPK (stream-ordered)

__device__ __forceinline__ void gl_lds16(const void* g, void* s) {
  __builtin_amdgcn_global_load_lds((const __attribute__((address_space(1))) u32*)g,
                                   (__attribute__((address_space(3))) u32*)s, 16, 0, 0);
}

#define VM4() asm volatile("s_waitcnt vmcnt(4)" ::: "memory")
#define VM0() asm volatile("s_waitcnt vmcnt(0)" ::: "memory")

__device__ __forceinline__ f16x8 cvt8(f32x4 a, f32x4 b) {
  f16x8 r;
  r[0] = (_Float16)a[0]; r[1] = (_Float16)a[1]; r[2] = (_Float16)a[2]; r[3] = (_Float16)a[3];
  r[4] = (_Float16)b[0]; r[5] = (_Float16)b[1]; r[6] = (_Float16)b[2]; r[7] = (_Float16)b[3];
  return r;
}

__global__ __launch_bounds__(256) void k_cvt(const float* __restrict__ in,
                                             _Float16* __restrict__ out, long n8) {
  long i = (long)blockIdx.x * 256 + threadIdx.x;
  const long stride = (long)gridDim.x * 256;
  for (; i < n8; i += stride) {
    f32x4 a = ((const f32x4*)in)[i * 2];
    f32x4 b = ((const f32x4*)in)[i * 2 + 1];
    ((f16x8*)out)[i] = cvt8(a, b);
  }
}

// pack [fc1_1 | fc1_2] -> wpk for 256-col tiles (4 wn-waves of 64):
// c = q&255: wn=(c>>6)&3, mat=(c>>5)&1, n1=(c>>4)&1, fr=c&15;
// f = (q>>8)*128 + wn*32 + n1*16 + fr.   [verified R16/R17]
__global__ __launch_bounds__(256) void k_cvtpack(const float* __restrict__ fc11,
                                                 const float* __restrict__ fc12,
                                                 _Float16* __restrict__ wpk) {
  const long total = (long)NE * NPK * 256;  // 8-elem chunks
  long i8 = (long)blockIdx.x * 256 + threadIdx.x;
  const long stride = (long)gridDim.x * 256;
  for (; i8 < total; i8 += stride) {
    int k8 = (int)(i8 & 255);
    long qe = i8 >> 8;
    int q = (int)(qe % NPK);
    int e = (int)(qe / NPK);
    int c = q & 255;
    int f = (q >> 8) * 128 + ((c >> 6) & 3) * 32 + ((c >> 4) & 1) * 16 + (c & 15);
    const float* src = ((c >> 5) & 1 ? fc12 : fc11) + ((size_t)e * FFN + f) * HD + k8 * 8;
    f32x4 a = *(const f32x4*)src;
    f32x4 b = *(const f32x4*)(src + 4);
    *(f16x8*)(wpk + qe * HD + (size_t)k8 * 8) = cvt8(a, b);
  }
}

__global__ __launch_bounds__(256) void k_prep(const float* __restrict__ wg,
                                              const float* __restrict__ wge,
                                              float* __restrict__ wr) {
  int i = blockIdx.x * 256 + threadIdx.x;
  if (i < HD * NE) wr[i] = 0.5f * (wge[i] + wg[i]);
}

// router + fused x -> fp16 conversion
__global__ __launch_bounds__(256) void k_router(const float* __restrict__ x,
                                                const float* __restrict__ wr,
                                                float* __restrict__ logits,
                                                float* __restrict__ tokw,
                                                int* __restrict__ lists,
                                                int* __restrict__ cnt,
                                                _Float16* __restrict__ xh) {
  const int t = blockIdx.x, tid = threadIdx.x;
  const float* xr = x + (size_t)t * HD;
  _Float16* xo = xh + (size_t)t * HD;
  float acc[NE];
#pragma unroll
  for (int e = 0; e < NE; ++e) acc[e] = 0.f;
  for (int h = tid; h < HD; h += 256) {
    float xv = xr[h];
    xo[h] = (_Float16)xv;
    const float* w = wr + h * NE;
#pragma unroll
    for (int e = 0; e < NE; ++e) acc[e] = fmaf(xv, w[e], acc[e]);
  }
#pragma unroll
  for (int e = 0; e < NE; ++e)
#pragma unroll
    for (int off = 32; off; off >>= 1)
      acc[e] += __shfl_xor(acc[e], off, 64);
  __shared__ float red[4][NE];
  int wv = tid >> 6;
  if ((tid & 63) == 0)
    for (int e = 0; e < NE; ++e) red[wv][e] = acc[e];
  __syncthreads();
  if (tid == 0) {
    float l[NE];
#pragma unroll
    for (int e = 0; e < NE; ++e) l[e] = red[0][e] + red[1][e] + red[2][e] + red[3][e];
#pragma unroll
    for (int e = 0; e < NE; ++e) logits[(size_t)t * NE + e] = l[e];
    int i0 = 0;
    for (int e = 1; e < NE; ++e) if (l[e] > l[i0]) i0 = e;
    int i1 = -1;
    for (int e = 0; e < NE; ++e) if (e != i0 && (i1 < 0 || l[e] > l[i1])) i1 = e;
    float p1 = __expf(l[i1] - l[i0]);
    float s = 1.f + p1;
    tokw[t * 2]     = 1.f / s;
    tokw[t * 2 + 1] = p1 / s;
    int q0 = atomicAdd(&cnt[i0], 1);
    lists[i0 * TT + q0] = t * 2;
    int q1 = atomicAdd(&cnt[i1], 1);
    lists[i1 * TT + q1] = t * 2 + 1;
  }
}

// ====== Stage A (R17-verified): act = silu(h1)*h2, h = xh @ wpk^T ======
// 256x256 tile, BK=32, 512 thr, 8 waves 2Mx4N (wave 128x64), mfma 16x16x32.
// 3-buffer ring, prefetch distance 2, ONE barrier + counted vmcnt(4) per K-step.
__global__ __launch_bounds__(512, 2) void k_ffn1(const _Float16* __restrict__ xh,
                                                 const _Float16* __restrict__ wpk,
                                                 const int* __restrict__ lists,
                                                 const int* __restrict__ cnt,
                                                 _Float16* __restrict__ act) {
  const int bid = blockIdx.x;
  const int xk = bid & 7;
  const int sq = bid >> 3;                 // 0..1407
  const int slot = sq / 88;                // 0..15
  const int within = sq - slot * 88;
  const int ct = within >> 1;              // 0..43
  const int rt_in = within & 1;
  const int e = slot & 7;
  const int r = ((xk - e) & 7) + ((slot >> 3) << 3);  // 0..15
  const int rt = r * 2 + rt_in;            // 0..31
  const int count = cnt[e];
  if (rt * 256 >= count) return;
  const int tid = threadIdx.x, lane = tid & 63, wv = tid >> 6;

  __shared__ __align__(16) _Float16 As[3][8192];   // 3 x (256 rows x 32 k)
  __shared__ __align__(16) _Float16 Bs[3][8192];
  __shared__ int row_pair[256];

  if (tid < 256) {
    int rg = rt * 256 + tid;
    row_pair[tid] = (rg < count) ? lists[e * TT + rg] : -1;
  }
  __syncthreads();

  const int lr = lane >> 2;
  const int r0 = wv * 16 + lr;                          // 0..127
  const int cp = (((lane & 3) ^ ((r0 >> 1) & 3))) * 8;  // +128 rows: same perm
  const int pr0 = row_pair[r0], pr1 = row_pair[r0 + 128];
  const _Float16* gA0 = xh + (size_t)(pr0 >= 0 ? (pr0 >> 1) : 0) * HD + cp;
  const _Float16* gA1 = xh + (size_t)(pr1 >= 0 ? (pr1 >> 1) : 0) * HD + cp;
  const _Float16* gB0 = wpk + ((size_t)e * NPK + (size_t)ct * 256 + r0) * HD + cp;
  const _Float16* gB1 = gB0 + (size_t)128 * HD;

  auto stgA = [&](int b, int k0) {
    gl_lds16(gA0 + k0, &As[b][wv * 512]);
    gl_lds16(gA1 + k0, &As[b][4096 + wv * 512]);
  };
  auto stgB = [&](int b, int k0) {
    gl_lds16(gB0 + k0, &Bs[b][wv * 512]);
    gl_lds16(gB1 + k0, &Bs[b][4096 + wv * 512]);
  };

  const f32x4 z4 = {0.f, 0.f, 0.f, 0.f};
  f32x4 acc[8][4];
#pragma unroll
  for (int m = 0; m < 8; ++m)
#pragma unroll
    for (int n = 0; n < 4; ++n) acc[m][n] = z4;

  const int fr = lane & 15, kq = lane >> 4;
  const int wm = wv >> 2, wn = wv & 3;
  int aoff[8], boff[4];
#pragma unroll
  for (int m = 0; m < 8; ++m) {
    int R = wm * 128 + m * 16 + fr;
    aoff[m] = R * 32 + (kq ^ ((R >> 1) & 3)) * 8;
  }
#pragma unroll
  for (int n = 0; n < 4; ++n) {
    int R = wn * 64 + n * 16 + fr;
    boff[n] = R * 32 + (kq ^ ((R >> 1) & 3)) * 8;
  }

  stgA(0, 0); stgB(0, 0);
  stgA(1, 32); stgB(1, 32);
  VM4();
  __builtin_amdgcn_s_barrier();

  const int NS = HD / 32;  // 64
  for (int s = 0; s < NS; ++s) {
    const int b = s % 3;
    const int pb = (s + 2) % 3;
    f16x8 fa[8], fb[4];
#pragma unroll
    for (int m = 0; m < 8; ++m) fa[m] = *(const f16x8*)&As[b][aoff[m]];
#pragma unroll
    for (int n = 0; n < 4; ++n) fb[n] = *(const f16x8*)&Bs[b][boff[n]];
    if (s + 2 < NS) { stgA(pb, (s + 2) * 32); stgB(pb, (s + 2) * 32); }
    __builtin_amdgcn_s_setprio(1);
#pragma unroll
    for (int m = 0; m < 8; ++m)
#pragma unroll
      for (int n = 0; n < 4; ++n)
        acc[m][n] = __builtin_amdgcn_mfma_f32_16x16x32_f16(fa[m], fb[n], acc[m][n], 0, 0, 0);
    __builtin_amdgcn_s_setprio(0);
    if (s < NS - 2) { VM4(); }
    else if (s == NS - 2) { VM0(); }
    __builtin_amdgcn_s_barrier();
  }

  const int rbase = wm * 128 + kq * 4;
#pragma unroll
  for (int m = 0; m < 8; ++m) {
#pragma unroll
    for (int n = 0; n < 2; ++n) {
      const int f = ct * 128 + wn * 32 + n * 16 + fr;
#pragma unroll
      for (int j = 0; j < 4; ++j) {
        int rl = rbase + m * 16 + j;
        int pr = row_pair[rl];
        if (pr >= 0) {
          float h1 = acc[m][n][j], h2 = acc[m][n + 2][j];
          float sv = h1 / (1.f + __expf(-h1));
          act[(size_t)pr * FFN + f] = (_Float16)(sv * h2);
        }
      }
    }
  }
}

// ============ Stage B: out += w * (act @ w3h^T). R12-exact: 192x128, wave 96x64 ============
__global__ __launch_bounds__(256, 3) void k_ffn2(const _Float16* __restrict__ act,
                                                 const _Float16* __restrict__ w3h,
                                                 const int* __restrict__ lists,
                                                 const int* __restrict__ cnt,
                                                 const float* __restrict__ tokw,
                                                 float* __restrict__ out) {
  const int bid = blockIdx.x;
  const int xk = bid & 7;
  const int sq = bid >> 3;                 // 0..703
  const int e = sq / 88;                   // 0..7
  const int within = sq - e * 88;
  const int rt = within >> 1;              // 0..43
  const int ct = (((xk - e) & 7) << 1) + (within & 1);  // 0..15
  const int count = cnt[e];
  if (rt * 192 >= count) return;
  const int tid = threadIdx.x, lane = tid & 63, wv = tid >> 6;

  __shared__ __align__(16) _Float16 As[2][6144];
  __shared__ __align__(16) _Float16 Bs[2][4096];
  __shared__ int row_pair[192];
  __shared__ float row_w[192];

  if (tid < 192) {
    int rg = rt * 192 + tid;
    int pr = (rg < count) ? lists[e * TT + rg] : -1;
    row_pair[tid] = pr;
    row_w[tid] = (pr >= 0) ? tokw[pr] : 0.f;
  }
  __syncthreads();

  const int lr = lane >> 2;
  const int srowA = wv * 48 + lr;
  const int cpA = (lane & 3) ^ ((srowA >> 1) & 3);
  const int pA0 = row_pair[srowA], pA1 = row_pair[srowA + 16], pA2 = row_pair[srowA + 32];
  const _Float16* gA0 = act + (size_t)(pA0 >= 0 ? pA0 : 0) * FFN + cpA * 8;
  const _Float16* gA1 = act + (size_t)(pA1 >= 0 ? pA1 : 0) * FFN + cpA * 8;
  const _Float16* gA2 = act + (size_t)(pA2 >= 0 ? pA2 : 0) * FFN + cpA * 8;
  const int srowB = wv * 32 + lr;
  const int cpB = (lane & 3) ^ ((srowB >> 1) & 3);
  const _Float16* gB0 = w3h + ((size_t)e * HD + (size_t)ct * 128 + srowB) * FFN + cpB * 8;
  const _Float16* gB1 = gB0 + (size_t)16 * FFN;

  auto stage = [&](int sl, int k0) {
    gl_lds16(gA0 + k0, &As[sl][wv * 1536]);
    gl_lds16(gA1 + k0, &As[sl][wv * 1536 + 512]);
    gl_lds16(gA2 + k0, &As[sl][wv * 1536 + 1024]);
    gl_lds16(gB0 + k0, &Bs[sl][wv * 1024]);
    gl_lds16(gB1 + k0, &Bs[sl][wv * 1024 + 512]);
  };

  const f32x4 z4 = {0.f, 0.f, 0.f, 0.f};
  f32x4 acc[6][4];
#pragma unroll
  for (int m = 0; m < 6; ++m)
#pragma unroll
    for (int n = 0; n < 4; ++n) acc[m][n] = z4;

  const int fr = lane & 15, kq = lane >> 4;
  const int wrow = (wv >> 1) * 96, wcol = (wv & 1) * 64;
  int aoff[6], boff[4];
#pragma unroll
  for (int m = 0; m < 6; ++m) {
    int rr = wrow + m * 16 + fr;
    aoff[m] = rr * 32 + (kq ^ ((rr >> 1) & 3)) * 8;
  }
#pragma unroll
  for (int n = 0; n < 4; ++n) {
    int rr = wcol + n * 16 + fr;
    boff[n] = rr * 32 + (kq ^ ((rr >> 1) & 3)) * 8;
  }

  stage(0, 0);
  __syncthreads();

  const int NS = FFN / 32;  // 176
  for (int ks = 0; ks < NS; ++ks) {
    const int buf = ks & 1;
    if (ks + 1 < NS) stage(buf ^ 1, (ks + 1) * 32);
    f16x8 fa[6], fb[4];
#pragma unroll
    for (int m = 0; m < 6; ++m) fa[m] = *(const f16x8*)&As[buf][aoff[m]];
#pragma unroll
    for (int n = 0; n < 4; ++n) fb[n] = *(const f16x8*)&Bs[buf][boff[n]];
    __builtin_amdgcn_s_setprio(1);
#pragma unroll
    for (int m = 0; m < 6; ++m)
#pragma unroll
      for (int n = 0; n < 4; ++n)
        acc[m][n] = __builtin_amdgcn_mfma_f32_16x16x32_f16(fa[m], fb[n], acc[m][n], 0, 0, 0);
    __builtin_amdgcn_s_setprio(0);
    __syncthreads();
  }

  const int rbase = wrow + kq * 4;
#pragma unroll
  for (int m = 0; m < 6; ++m) {
#pragma unroll
    for (int n = 0; n < 4; ++n) {
      const int col = ct * 128 + wcol + n * 16 + fr;
#pragma unroll
      for (int j = 0; j < 4; ++j) {
        int rl = rbase + m * 16 + j;
        int pr = row_pair[rl];
        if (pr >= 0) {
          float v = acc[m][n][j] * row_w[rl];
          unsafeAtomicAdd(out + (size_t)(pr >> 1) * HD + col, v);
        }
      }
    }
  }
}

extern "C" void kernel_launch(void* const* d_in, const int* in_sizes, int n_in,
                              void* d_out, int out_size, void* d_ws, size_t ws_size,
                              hipStream_t stream) {
  (void)in_sizes; (void)n_in; (void)out_size; (void)ws_size;
  const float* x    = (const float*)d_in[0];
  const float* wg   = (const float*)d_in[1];
  const float* wge  = (const float*)d_in[2];
  const float* fc11 = (const float*)d_in[3];
  const float* fc12 = (const float*)d_in[4];
  const float* fc2  = (const float*)d_in[5];
  float* out    = (float*)d_out;
  float* logits = out + (size_t)TT * HD;

  char* ws = (char*)d_ws;
  float* wr      = (float*)(ws + OFF_WR);
  int*   cnt     = (int*)(ws + OFF_CNT);
  int*   lists   = (int*)(ws + OFF_LISTS);
  float* tokw    = (float*)(ws + OFF_TOKW);
  _Float16* act  = (_Float16*)(ws + OFF_ACT);
  _Float16* xh   = (_Float16*)(ws + OFF_XH);
  _Float16* wpk  = (_Float16*)(ws + OFF_WPK);
  _Float16* w3h  = (_Float16*)(ws + OFF_W3H);

  hipMemsetAsync(out, 0, (size_t)TT * HD * sizeof(float), stream);
  hipMemsetAsync(cnt, 0, NE * sizeof(int), stream);

  k_prep<<<dim3((HD * NE + 255) / 256), 256, 0, stream>>>(wg, wge, wr);
  k_router<<<dim3(TT), 256, 0, stream>>>(x, wr, logits, tokw, lists, cnt, xh);

  k_cvtpack<<<dim3(2048), 256, 0, stream>>>(fc11, fc12, wpk);

  // grid = xk(8) x slot(16) x within(88); 512 threads (8 waves)
  k_ffn1<<<dim3(8 * 16 * 88), 512, 0, stream>>>(xh, wpk, lists, cnt, act);

  // w3h reuses the wpk region — stream-ordered after ffn1 finished reading it
  k_cvt<<<dim3(2048), 256, 0, stream>>>(fc2, w3h, (long)NE * HD * FFN / 8);

  k_ffn2<<<dim3(8 * 8 * 88), 256, 0, stream>>>(act, w3h, lists, cnt, tokw, out);
}